// Round 5
// baseline (372.467 us; speedup 1.0000x reference)
//
#include <hip/hip_runtime.h>

// GCN 2-layer + linear head on MI355X.
// R4 post-mortem: aggregate (2x63us, FETCH 151MB @2.4TB/s L2-miss fill) is
// near structural floor for a uniform random graph. Remaining fat is the
// sort chain: 153-block grids (60% GPU idle) + scattered 4B bucket writes.
// R5: CHUNK=2048 (611 blocks), LDS-staged chunk-local counting sort with
// coalesced run flushes, 512-thread k_csr, 8-deep unrolled aggregate gather.

constexpr int NB_SHIFT = 8;                 // 256 nodes per bucket
constexpr int BUCK_NODES = 1 << NB_SHIFT;
constexpr int CHUNK = 2048;                 // edges per sort block
constexpr int STPB = 512;                   // sort threads per block
// nbuck = ceil(n/256) = 391 for n=100k; code assumes nbuck <= 512.

// ---- A: per-chunk histogram of dst>>NB_SHIFT (LDS atomics only) --------
__global__ __launch_bounds__(STPB) void k_bhist(const int* __restrict__ dst, int E, int nbuck,
                                                int* __restrict__ blockHist) {
    __shared__ int sh[512];
    for (int i = threadIdx.x; i < nbuck; i += STPB) sh[i] = 0;
    __syncthreads();
    int base = blockIdx.x * CHUNK;
    int end = min(base + CHUNK, E);
    for (int e = base + threadIdx.x; e < end; e += STPB)
        atomicAdd(&sh[dst[e] >> NB_SHIFT], 1);
    __syncthreads();
    int* out = blockHist + (size_t)blockIdx.x * nbuck;
    for (int i = threadIdx.x; i < nbuck; i += STPB) out[i] = sh[i];
}

// ---- B: column scan of blockHist (in place -> per-chunk offsets) + bucket bases
__global__ __launch_bounds__(512) void k_boffsets(int* __restrict__ blockHist, int nchunks,
                                                  int nbuck, int* __restrict__ bucketBase) {
    __shared__ int tot[512];
    int b = threadIdx.x;
    int run = 0;
    if (b < nbuck) {
        for (int c = 0; c < nchunks; ++c) {
            size_t idx = (size_t)c * nbuck + b;   // coalesced across threads
            int v = blockHist[idx];
            blockHist[idx] = run;                 // exclusive within-bucket prefix
            run += v;
        }
    }
    tot[b] = (b < nbuck) ? run : 0;
    __syncthreads();
    for (int s = 1; s < 512; s <<= 1) {
        int add = (b >= s) ? tot[b - s] : 0;
        __syncthreads();
        tot[b] += add;
        __syncthreads();
    }
    if (b < nbuck) {
        bucketBase[b] = tot[b] - run;             // exclusive
        if (b == nbuck - 1) bucketBase[nbuck] = tot[b];
    }
}

// ---- C: chunk-local LDS counting sort by bucket, coalesced run flush ---
__global__ __launch_bounds__(STPB) void k_bsort(const int* __restrict__ src,
                                                const int* __restrict__ dst, int E, int nbuck,
                                                const int* __restrict__ blockHist,
                                                const int* __restrict__ bucketBase,
                                                unsigned* __restrict__ packed) {
    __shared__ int scn[512];
    __shared__ int shStart[512];
    __shared__ int shCur[512];
    __shared__ int shOff[512];
    __shared__ unsigned stage[CHUNK];
    __shared__ unsigned short sbkt[CHUNK];
    const int tid = threadIdx.x;
    const int base = blockIdx.x * CHUNK;
    const int end = min(base + CHUNK, E);
    // pass A: count buckets in this chunk
    shCur[tid] = 0;   // reuse as counter
    __syncthreads();
    for (int e = base + tid; e < end; e += STPB)
        atomicAdd(&shCur[dst[e] >> NB_SHIFT], 1);
    __syncthreads();
    // exclusive scan over buckets (LDS slot layout)
    int v = (tid < nbuck) ? shCur[tid] : 0;
    scn[tid] = v;
    __syncthreads();
    for (int s = 1; s < 512; s <<= 1) {
        int a = (tid >= s) ? scn[tid - s] : 0;
        __syncthreads();
        scn[tid] += a;
        __syncthreads();
    }
    shStart[tid] = scn[tid] - v;
    shCur[tid] = scn[tid] - v;
    if (tid < nbuck)
        shOff[tid] = bucketBase[tid] + blockHist[(size_t)blockIdx.x * nbuck + tid];
    __syncthreads();
    // pass B: permute chunk into LDS, bucket-major
    for (int e = base + tid; e < end; e += STPB) {
        int s = src[e];
        int d = dst[e];
        int b = d >> NB_SHIFT;
        int slot = atomicAdd(&shCur[b], 1);
        stage[slot] = ((unsigned)(d & (BUCK_NODES - 1)) << 17) | (unsigned)s;
        sbkt[slot] = (unsigned short)b;
    }
    __syncthreads();
    // pass C: linear flush -> consecutive threads write consecutive slots
    // of the same bucket run (coalesced, low line amplification)
    int cnt = end - base;
    for (int i = tid; i < cnt; i += STPB) {
        int b = sbkt[i];
        packed[shOff[b] + (i - shStart[b])] = stage[i];
    }
}

// ---- D: per-bucket counting sort by dstLocal -> CSR + rowptr + dinv ----
__global__ __launch_bounds__(512) void k_csr(const unsigned* __restrict__ packed,
                                             const int* __restrict__ bucketBase, int n, int E,
                                             int* __restrict__ csr, int* __restrict__ rowptr,
                                             float* __restrict__ dinv) {
    __shared__ int cnt[BUCK_NODES];
    __shared__ int scn[BUCK_NODES];
    __shared__ int cur[BUCK_NODES];
    const int tid = threadIdx.x;
    const int e0 = bucketBase[blockIdx.x], e1 = bucketBase[blockIdx.x + 1];
    if (tid < BUCK_NODES) cnt[tid] = 0;
    __syncthreads();
    for (int e = e0 + tid; e < e1; e += 512)
        atomicAdd(&cnt[packed[e] >> 17], 1);
    __syncthreads();
    int v = (tid < BUCK_NODES) ? cnt[tid] : 0;
    if (tid < BUCK_NODES) scn[tid] = v;
    __syncthreads();
    for (int s = 1; s < BUCK_NODES; s <<= 1) {   // inclusive Hillis-Steele
        int add = (tid >= s && tid < BUCK_NODES) ? scn[tid - s] : 0;
        __syncthreads();
        if (tid < BUCK_NODES) scn[tid] += add;
        __syncthreads();
    }
    if (tid < BUCK_NODES) {
        int exc = e0 + scn[tid] - v;
        cur[tid] = exc;
        int node = blockIdx.x * BUCK_NODES + tid;
        if (node < n) {
            rowptr[node] = exc;
            dinv[node] = rsqrtf(1.0f + (float)v);
        }
    }
    if (blockIdx.x == gridDim.x - 1 && tid == 0) rowptr[n] = E;
    __syncthreads();
    for (int e = e0 + tid; e < e1; e += 512) {
        unsigned p = packed[e];
        int pos = atomicAdd(&cur[p >> 17], 1);   // LDS cursor
        csr[pos] = (int)(p & 0x1FFFFu);          // dense ~13KB window, L2-hot
    }
}

// ---- GEMM: out[i][f] = (sum_k A[i][k] * W[k][f]) * dinv[i] -------------
__global__ __launch_bounds__(256) void k_gemm64(const float* __restrict__ A, const float* __restrict__ W,
                                                const float* __restrict__ dinv, float* __restrict__ out,
                                                int n) {
    const int lane = threadIdx.x & 63;
    const int wave = threadIdx.x >> 6;
    float wcol[64];
#pragma unroll
    for (int k = 0; k < 64; ++k) wcol[k] = W[k * 64 + lane];
    int base = blockIdx.x * 64;
    for (int r = wave; r < 64; r += 4) {
        int row = base + r;
        if (row >= n) break;
        float a = A[(size_t)row * 64 + lane];
        float acc = 0.0f;
#pragma unroll
        for (int k = 0; k < 64; ++k) {
            float ak = __uint_as_float(__builtin_amdgcn_readlane(__float_as_uint(a), k));
            acc = fmaf(ak, wcol[k], acc);
        }
        out[(size_t)row * 64 + lane] = acc * dinv[row];
    }
}

// ---- Aggregate: one wave per node, register accumulator, no atomics ----
// out[i][f] = relu(dinv[i]*(g[i][f] + sum_nb g[s][f]) + b[f]); LAST fuses head.
template <bool LAST>
__global__ __launch_bounds__(256) void k_aggregate(const float* __restrict__ g,
                                                   const int* __restrict__ rowptr,
                                                   const int* __restrict__ csr,
                                                   const float* __restrict__ dinv,
                                                   const float* __restrict__ bias,
                                                   const float* __restrict__ Wo,
                                                   const float* __restrict__ bo,
                                                   float* __restrict__ out, int n) {
    int t = blockIdx.x * blockDim.x + threadIdx.x;
    int node = t >> 6;
    int lane = t & 63;
    if (node >= n) return;
    int e = rowptr[node];
    int e1 = rowptr[node + 1];
    float acc = g[(size_t)node * 64 + lane];  // self-loop term
    // 8 gathers in flight per wave (MLP)
    for (; e + 8 <= e1; e += 8) {
        int idx[8];
        float a[8];
#pragma unroll
        for (int k = 0; k < 8; ++k) idx[k] = csr[e + k];
#pragma unroll
        for (int k = 0; k < 8; ++k) a[k] = g[(size_t)idx[k] * 64 + lane];
        acc += ((a[0] + a[1]) + (a[2] + a[3])) + ((a[4] + a[5]) + (a[6] + a[7]));
    }
    for (; e < e1; ++e) acc += g[(size_t)csr[e] * 64 + lane];
    float vv = fmaxf(fmaf(dinv[node], acc, bias[lane]), 0.0f);
    if constexpr (LAST) {
        float p = vv * Wo[lane];
#pragma unroll
        for (int s = 32; s > 0; s >>= 1) p += __shfl_xor(p, s, 64);
        if (lane == 0) out[node] = p + bo[0];
    } else {
        out[(size_t)node * 64 + lane] = vv;
    }
}

extern "C" void kernel_launch(void* const* d_in, const int* in_sizes, int n_in,
                              void* d_out, int out_size, void* d_ws, size_t ws_size,
                              hipStream_t stream) {
    const float* x  = (const float*)d_in[0];
    const int*   ei = (const int*)d_in[1];
    const float* W1 = (const float*)d_in[2];
    const float* b1 = (const float*)d_in[3];
    const float* W2 = (const float*)d_in[4];
    const float* b2 = (const float*)d_in[5];
    const float* Wo = (const float*)d_in[6];
    const float* bo = (const float*)d_in[7];
    float* out = (float*)d_out;

    const int n = in_sizes[0] / 64;
    const int E = in_sizes[1] / 2;
    const int* src = ei;
    const int* dst = ei + E;

    const int nbuck = (n + BUCK_NODES - 1) >> NB_SHIFT;      // 391
    const int nchunks = (E + CHUNK - 1) / CHUNK;             // 611

    char* ws = (char*)d_ws;
    size_t off = 0;
    auto alloc = [&](size_t bytes) -> void* {
        void* p = ws + off;
        off += (bytes + 255) & ~(size_t)255;
        return p;
    };
    float*    dinv       = (float*)alloc((size_t)n * 4);
    int*      bucketBase = (int*)alloc((size_t)(nbuck + 1) * 4);
    int*      blockHist  = (int*)alloc((size_t)nchunks * nbuck * 4);
    unsigned* packed     = (unsigned*)alloc((size_t)E * 4);
    int*      csr        = (int*)alloc((size_t)E * 4);
    int*      rowptr     = (int*)alloc((size_t)(n + 1) * 4);
    float*    bufG       = (float*)alloc((size_t)n * 64 * 4);
    float*    bufH       = (float*)alloc((size_t)n * 64 * 4);

    // ---- bucketed counting sort -> dst-sorted CSR + rowptr + dinv ----
    k_bhist<<<nchunks, STPB, 0, stream>>>(dst, E, nbuck, blockHist);
    k_boffsets<<<1, 512, 0, stream>>>(blockHist, nchunks, nbuck, bucketBase);
    k_bsort<<<nchunks, STPB, 0, stream>>>(src, dst, E, nbuck, blockHist, bucketBase, packed);
    k_csr<<<nbuck, 512, 0, stream>>>(packed, bucketBase, n, E, csr, rowptr, dinv);

    const int gemmGrid = (n + 63) / 64;
    const int nodeGrid = (n * 64 + 255) / 256;

    // ---- layer 1 ----
    k_gemm64<<<gemmGrid, 256, 0, stream>>>(x, W1, dinv, bufG, n);
    k_aggregate<false><<<nodeGrid, 256, 0, stream>>>(bufG, rowptr, csr, dinv, b1,
                                                     nullptr, nullptr, bufH, n);
    // ---- layer 2 (head fused into epilogue) ----
    k_gemm64<<<gemmGrid, 256, 0, stream>>>(bufH, W2, dinv, bufG, n);
    k_aggregate<true><<<nodeGrid, 256, 0, stream>>>(bufG, rowptr, csr, dinv, b2,
                                                    Wo, bo, out, n);
}

// Round 6
// 235.815 us; speedup vs baseline: 1.5795x; 1.5795x over previous
//
#include <hip/hip_runtime.h>

// GCN 2-layer + linear head on MI355X.
// R5 post-mortem: single-block k_boffsets serial-scanned 611 chunk rows ->
// 149us latency chain on one CU. R6: parallel column scan (one block per
// bucket over chunk counts in LDS) + tiny base scan. Sort chain otherwise
// unchanged (LDS-staged counting sort, dense writes).

constexpr int NB_SHIFT = 8;                 // 256 nodes per bucket
constexpr int BUCK_NODES = 1 << NB_SHIFT;
constexpr int CHUNK = 2048;                 // edges per sort block
constexpr int STPB = 512;                   // sort threads per block
// assumes: nbuck <= 512, nchunks <= 1024

// ---- A: per-chunk histogram of dst>>NB_SHIFT (LDS atomics only) --------
__global__ __launch_bounds__(STPB) void k_bhist(const int* __restrict__ dst, int E, int nbuck,
                                                int* __restrict__ blockHist) {
    __shared__ int sh[512];
    for (int i = threadIdx.x; i < nbuck; i += STPB) sh[i] = 0;
    __syncthreads();
    int base = blockIdx.x * CHUNK;
    int end = min(base + CHUNK, E);
    for (int e = base + threadIdx.x; e < end; e += STPB)
        atomicAdd(&sh[dst[e] >> NB_SHIFT], 1);
    __syncthreads();
    int* out = blockHist + (size_t)blockIdx.x * nbuck;
    for (int i = threadIdx.x; i < nbuck; i += STPB) out[i] = sh[i];
}

// ---- B1: per-bucket parallel scan over chunk counts (one block/bucket) -
__global__ __launch_bounds__(1024) void k_colscan(int* __restrict__ blockHist, int nchunks,
                                                  int nbuck, int* __restrict__ bucketTot) {
    __shared__ int sh[1024];
    const int b = blockIdx.x;
    const int tid = threadIdx.x;
    int v = (tid < nchunks) ? blockHist[(size_t)tid * nbuck + b] : 0;
    sh[tid] = v;
    __syncthreads();
    for (int s = 1; s < 1024; s <<= 1) {     // inclusive Hillis-Steele
        int a = (tid >= s) ? sh[tid - s] : 0;
        __syncthreads();
        sh[tid] += a;
        __syncthreads();
    }
    if (tid < nchunks) blockHist[(size_t)tid * nbuck + b] = sh[tid] - v;  // exclusive
    if (tid == nchunks - 1) bucketTot[b] = sh[tid];
}

// ---- B2: exclusive scan of bucket totals -> bucketBase -----------------
__global__ __launch_bounds__(512) void k_base(const int* __restrict__ bucketTot, int nbuck,
                                              int E, int* __restrict__ bucketBase) {
    __shared__ int sh[512];
    const int tid = threadIdx.x;
    int v = (tid < nbuck) ? bucketTot[tid] : 0;
    sh[tid] = v;
    __syncthreads();
    for (int s = 1; s < 512; s <<= 1) {
        int a = (tid >= s) ? sh[tid - s] : 0;
        __syncthreads();
        sh[tid] += a;
        __syncthreads();
    }
    if (tid < nbuck) bucketBase[tid] = sh[tid] - v;
    if (tid == 0) bucketBase[nbuck] = E;
}

// ---- C: chunk-local LDS counting sort by bucket, coalesced run flush ---
__global__ __launch_bounds__(STPB) void k_bsort(const int* __restrict__ src,
                                                const int* __restrict__ dst, int E, int nbuck,
                                                const int* __restrict__ blockHist,
                                                const int* __restrict__ bucketBase,
                                                unsigned* __restrict__ packed) {
    __shared__ int scn[512];
    __shared__ int shStart[512];
    __shared__ int shCur[512];
    __shared__ int shOff[512];
    __shared__ unsigned stage[CHUNK];
    __shared__ unsigned short sbkt[CHUNK];
    const int tid = threadIdx.x;
    const int base = blockIdx.x * CHUNK;
    const int end = min(base + CHUNK, E);
    // pass A: count buckets in this chunk
    shCur[tid] = 0;   // reuse as counter
    __syncthreads();
    for (int e = base + tid; e < end; e += STPB)
        atomicAdd(&shCur[dst[e] >> NB_SHIFT], 1);
    __syncthreads();
    // exclusive scan over buckets
    int v = (tid < nbuck) ? shCur[tid] : 0;
    scn[tid] = v;
    __syncthreads();
    for (int s = 1; s < 512; s <<= 1) {
        int a = (tid >= s) ? scn[tid - s] : 0;
        __syncthreads();
        scn[tid] += a;
        __syncthreads();
    }
    shStart[tid] = scn[tid] - v;
    shCur[tid] = scn[tid] - v;
    if (tid < nbuck)
        shOff[tid] = bucketBase[tid] + blockHist[(size_t)blockIdx.x * nbuck + tid];
    __syncthreads();
    // pass B: permute chunk into LDS, bucket-major
    for (int e = base + tid; e < end; e += STPB) {
        int s = src[e];
        int d = dst[e];
        int b = d >> NB_SHIFT;
        int slot = atomicAdd(&shCur[b], 1);
        stage[slot] = ((unsigned)(d & (BUCK_NODES - 1)) << 17) | (unsigned)s;
        sbkt[slot] = (unsigned short)b;
    }
    __syncthreads();
    // pass C: linear flush -> consecutive threads write consecutive slots
    // of the same bucket run (coalesced, low line amplification)
    int cnt = end - base;
    for (int i = tid; i < cnt; i += STPB) {
        int b = sbkt[i];
        packed[shOff[b] + (i - shStart[b])] = stage[i];
    }
}

// ---- D: per-bucket counting sort by dstLocal -> CSR + rowptr + dinv ----
__global__ __launch_bounds__(512) void k_csr(const unsigned* __restrict__ packed,
                                             const int* __restrict__ bucketBase, int n, int E,
                                             int* __restrict__ csr, int* __restrict__ rowptr,
                                             float* __restrict__ dinv) {
    __shared__ int cnt[BUCK_NODES];
    __shared__ int scn[BUCK_NODES];
    __shared__ int cur[BUCK_NODES];
    const int tid = threadIdx.x;
    const int e0 = bucketBase[blockIdx.x], e1 = bucketBase[blockIdx.x + 1];
    if (tid < BUCK_NODES) cnt[tid] = 0;
    __syncthreads();
    for (int e = e0 + tid; e < e1; e += 512)
        atomicAdd(&cnt[packed[e] >> 17], 1);
    __syncthreads();
    int v = (tid < BUCK_NODES) ? cnt[tid] : 0;
    if (tid < BUCK_NODES) scn[tid] = v;
    __syncthreads();
    for (int s = 1; s < BUCK_NODES; s <<= 1) {   // inclusive Hillis-Steele
        int add = (tid >= s && tid < BUCK_NODES) ? scn[tid - s] : 0;
        __syncthreads();
        if (tid < BUCK_NODES) scn[tid] += add;
        __syncthreads();
    }
    if (tid < BUCK_NODES) {
        int exc = e0 + scn[tid] - v;
        cur[tid] = exc;
        int node = blockIdx.x * BUCK_NODES + tid;
        if (node < n) {
            rowptr[node] = exc;
            dinv[node] = rsqrtf(1.0f + (float)v);
        }
    }
    if (blockIdx.x == gridDim.x - 1 && tid == 0) rowptr[n] = E;
    __syncthreads();
    for (int e = e0 + tid; e < e1; e += 512) {
        unsigned p = packed[e];
        int pos = atomicAdd(&cur[p >> 17], 1);   // LDS cursor
        csr[pos] = (int)(p & 0x1FFFFu);          // dense ~13KB window, L2-hot
    }
}

// ---- GEMM: out[i][f] = (sum_k A[i][k] * W[k][f]) * dinv[i] -------------
__global__ __launch_bounds__(256) void k_gemm64(const float* __restrict__ A, const float* __restrict__ W,
                                                const float* __restrict__ dinv, float* __restrict__ out,
                                                int n) {
    const int lane = threadIdx.x & 63;
    const int wave = threadIdx.x >> 6;
    float wcol[64];
#pragma unroll
    for (int k = 0; k < 64; ++k) wcol[k] = W[k * 64 + lane];
    int base = blockIdx.x * 64;
    for (int r = wave; r < 64; r += 4) {
        int row = base + r;
        if (row >= n) break;
        float a = A[(size_t)row * 64 + lane];
        float acc = 0.0f;
#pragma unroll
        for (int k = 0; k < 64; ++k) {
            float ak = __uint_as_float(__builtin_amdgcn_readlane(__float_as_uint(a), k));
            acc = fmaf(ak, wcol[k], acc);
        }
        out[(size_t)row * 64 + lane] = acc * dinv[row];
    }
}

// ---- Aggregate: one wave per node, register accumulator, no atomics ----
// out[i][f] = relu(dinv[i]*(g[i][f] + sum_nb g[s][f]) + b[f]); LAST fuses head.
template <bool LAST>
__global__ __launch_bounds__(256) void k_aggregate(const float* __restrict__ g,
                                                   const int* __restrict__ rowptr,
                                                   const int* __restrict__ csr,
                                                   const float* __restrict__ dinv,
                                                   const float* __restrict__ bias,
                                                   const float* __restrict__ Wo,
                                                   const float* __restrict__ bo,
                                                   float* __restrict__ out, int n) {
    int t = blockIdx.x * blockDim.x + threadIdx.x;
    int node = t >> 6;
    int lane = t & 63;
    if (node >= n) return;
    int e = rowptr[node];
    int e1 = rowptr[node + 1];
    float acc = g[(size_t)node * 64 + lane];  // self-loop term
    // 8 gathers in flight per wave (MLP)
    for (; e + 8 <= e1; e += 8) {
        int idx[8];
        float a[8];
#pragma unroll
        for (int k = 0; k < 8; ++k) idx[k] = csr[e + k];
#pragma unroll
        for (int k = 0; k < 8; ++k) a[k] = g[(size_t)idx[k] * 64 + lane];
        acc += ((a[0] + a[1]) + (a[2] + a[3])) + ((a[4] + a[5]) + (a[6] + a[7]));
    }
    for (; e < e1; ++e) acc += g[(size_t)csr[e] * 64 + lane];
    float vv = fmaxf(fmaf(dinv[node], acc, bias[lane]), 0.0f);
    if constexpr (LAST) {
        float p = vv * Wo[lane];
#pragma unroll
        for (int s = 32; s > 0; s >>= 1) p += __shfl_xor(p, s, 64);
        if (lane == 0) out[node] = p + bo[0];
    } else {
        out[(size_t)node * 64 + lane] = vv;
    }
}

extern "C" void kernel_launch(void* const* d_in, const int* in_sizes, int n_in,
                              void* d_out, int out_size, void* d_ws, size_t ws_size,
                              hipStream_t stream) {
    const float* x  = (const float*)d_in[0];
    const int*   ei = (const int*)d_in[1];
    const float* W1 = (const float*)d_in[2];
    const float* b1 = (const float*)d_in[3];
    const float* W2 = (const float*)d_in[4];
    const float* b2 = (const float*)d_in[5];
    const float* Wo = (const float*)d_in[6];
    const float* bo = (const float*)d_in[7];
    float* out = (float*)d_out;

    const int n = in_sizes[0] / 64;
    const int E = in_sizes[1] / 2;
    const int* src = ei;
    const int* dst = ei + E;

    const int nbuck = (n + BUCK_NODES - 1) >> NB_SHIFT;      // 391
    const int nchunks = (E + CHUNK - 1) / CHUNK;             // 611

    char* ws = (char*)d_ws;
    size_t off = 0;
    auto alloc = [&](size_t bytes) -> void* {
        void* p = ws + off;
        off += (bytes + 255) & ~(size_t)255;
        return p;
    };
    float*    dinv       = (float*)alloc((size_t)n * 4);
    int*      bucketBase = (int*)alloc((size_t)(nbuck + 1) * 4);
    int*      bucketTot  = (int*)alloc((size_t)nbuck * 4);
    int*      blockHist  = (int*)alloc((size_t)nchunks * nbuck * 4);
    unsigned* packed     = (unsigned*)alloc((size_t)E * 4);
    int*      csr        = (int*)alloc((size_t)E * 4);
    int*      rowptr     = (int*)alloc((size_t)(n + 1) * 4);
    float*    bufG       = (float*)alloc((size_t)n * 64 * 4);
    float*    bufH       = (float*)alloc((size_t)n * 64 * 4);

    // ---- bucketed counting sort -> dst-sorted CSR + rowptr + dinv ----
    k_bhist<<<nchunks, STPB, 0, stream>>>(dst, E, nbuck, blockHist);
    k_colscan<<<nbuck, 1024, 0, stream>>>(blockHist, nchunks, nbuck, bucketTot);
    k_base<<<1, 512, 0, stream>>>(bucketTot, nbuck, E, bucketBase);
    k_bsort<<<nchunks, STPB, 0, stream>>>(src, dst, E, nbuck, blockHist, bucketBase, packed);
    k_csr<<<nbuck, 512, 0, stream>>>(packed, bucketBase, n, E, csr, rowptr, dinv);

    const int gemmGrid = (n + 63) / 64;
    const int nodeGrid = (n * 64 + 255) / 256;

    // ---- layer 1 ----
    k_gemm64<<<gemmGrid, 256, 0, stream>>>(x, W1, dinv, bufG, n);
    k_aggregate<false><<<nodeGrid, 256, 0, stream>>>(bufG, rowptr, csr, dinv, b1,
                                                     nullptr, nullptr, bufH, n);
    // ---- layer 2 (head fused into epilogue) ----
    k_gemm64<<<gemmGrid, 256, 0, stream>>>(bufH, W2, dinv, bufG, n);
    k_aggregate<true><<<nodeGrid, 256, 0, stream>>>(bufG, rowptr, csr, dinv, b2,
                                                    Wo, bo, out, n);
}

// Round 7
// 224.341 us; speedup vs baseline: 1.6603x; 1.0511x over previous
//
#include <hip/hip_runtime.h>

// GCN 2-layer + linear head on MI355X.
// R6 post-mortem: sort chain (5 kernels, 3 edge passes, 3 scans) ~75us for
// ~30MB of traffic; 8-deep agg unroll regressed 63->68us (VGPR 12->20).
// R7: slab-allocated buckets (CAP=4096/bucket). k_bsort self-reserves slab
// space via one global atomicAdd per (chunk,bucket) -> deletes bhist/colscan/
// base + blockHist. k_csr emits (start,count) rowinfo. Agg back to 4-deep.

constexpr int NB_SHIFT = 8;                 // 256 nodes per bucket
constexpr int BUCK_NODES = 1 << NB_SHIFT;
constexpr int CAP = 4096;                   // slab capacity (mean 3197, +16 sigma)
constexpr int CHUNK = 4096;                 // edges per sort block
constexpr int STPB = 512;
// assumes nbuck <= 512, src < 2^17, CAP >= max bucket size

// ---- init slab cursors -------------------------------------------------
__global__ void k_binit(int* __restrict__ gcur, int nbuck) {
    int b = blockIdx.x * blockDim.x + threadIdx.x;
    if (b < nbuck) gcur[b] = b * CAP;
}

// ---- fused: chunk histogram -> slab reserve -> LDS sort -> dense flush -
__global__ __launch_bounds__(STPB) void k_bsort(const int* __restrict__ src,
                                                const int* __restrict__ dst, int E, int nbuck,
                                                int* __restrict__ gcur,
                                                unsigned* __restrict__ packed) {
    __shared__ int shStart[512];
    __shared__ int shCur[512];
    __shared__ int shOff[512];
    __shared__ unsigned stage[CHUNK];
    __shared__ unsigned short sbkt[CHUNK];
    const int tid = threadIdx.x;
    const int base = blockIdx.x * CHUNK;
    const int end = min(base + CHUNK, E);
    // pass A: count buckets in this chunk (LDS atomics)
    shCur[tid] = 0;
    __syncthreads();
    for (int e = base + tid; e < end; e += STPB)
        atomicAdd(&shCur[dst[e] >> NB_SHIFT], 1);
    __syncthreads();
    int v = shCur[tid];
    shStart[tid] = v;
    __syncthreads();
    for (int s = 1; s < 512; s <<= 1) {      // inclusive Hillis-Steele
        int a = (tid >= s) ? shStart[tid - s] : 0;
        __syncthreads();
        shStart[tid] += a;
        __syncthreads();
    }
    int exc = shStart[tid] - v;
    shStart[tid] = exc;
    shCur[tid] = exc;
    // reserve this chunk's span in bucket slabs (one global atomic each)
    if (tid < nbuck) shOff[tid] = (v > 0) ? atomicAdd(&gcur[tid], v) : 0;
    __syncthreads();
    // pass B: permute chunk into LDS, bucket-major
    for (int e = base + tid; e < end; e += STPB) {
        int s = src[e];
        int d = dst[e];
        int b = d >> NB_SHIFT;
        int slot = atomicAdd(&shCur[b], 1);
        stage[slot] = ((unsigned)(d & (BUCK_NODES - 1)) << 17) | (unsigned)s;
        sbkt[slot] = (unsigned short)b;
    }
    __syncthreads();
    // pass C: linear flush, same-bucket runs (~10 edges) land contiguously
    int cnt = end - base;
    for (int i = tid; i < cnt; i += STPB) {
        int b = sbkt[i];
        packed[shOff[b] + (i - shStart[b])] = stage[i];
    }
}

// ---- per-bucket counting sort by dstLocal -> csr slab + rowinfo + dinv -
__global__ __launch_bounds__(512) void k_csr(const unsigned* __restrict__ packed,
                                             const int* __restrict__ gcur, int n,
                                             int* __restrict__ csr, int2* __restrict__ rowinfo,
                                             float* __restrict__ dinv) {
    __shared__ int cnt[BUCK_NODES];
    __shared__ int scn[BUCK_NODES];
    __shared__ int cur[BUCK_NODES];
    const int tid = threadIdx.x;
    const int e0 = blockIdx.x * CAP;
    const int e1 = gcur[blockIdx.x];          // slab base + size
    if (tid < BUCK_NODES) cnt[tid] = 0;
    __syncthreads();
    for (int e = e0 + tid; e < e1; e += 512)
        atomicAdd(&cnt[packed[e] >> 17], 1);
    __syncthreads();
    int v = (tid < BUCK_NODES) ? cnt[tid] : 0;
    if (tid < BUCK_NODES) scn[tid] = v;
    __syncthreads();
    for (int s = 1; s < BUCK_NODES; s <<= 1) {   // inclusive Hillis-Steele
        int add = (tid >= s && tid < BUCK_NODES) ? scn[tid - s] : 0;
        __syncthreads();
        if (tid < BUCK_NODES) scn[tid] += add;
        __syncthreads();
    }
    if (tid < BUCK_NODES) {
        int exc = e0 + scn[tid] - v;
        cur[tid] = exc;
        int node = blockIdx.x * BUCK_NODES + tid;
        if (node < n) {
            rowinfo[node] = make_int2(exc, v);
            dinv[node] = rsqrtf(1.0f + (float)v);
        }
    }
    __syncthreads();
    for (int e = e0 + tid; e < e1; e += 512) {
        unsigned p = packed[e];
        int pos = atomicAdd(&cur[p >> 17], 1);   // LDS cursor
        csr[pos] = (int)(p & 0x1FFFFu);          // dense slab window, L2-hot
    }
}

// ---- GEMM: out[i][f] = (sum_k A[i][k] * W[k][f]) * dinv[i] -------------
__global__ __launch_bounds__(256) void k_gemm64(const float* __restrict__ A, const float* __restrict__ W,
                                                const float* __restrict__ dinv, float* __restrict__ out,
                                                int n) {
    const int lane = threadIdx.x & 63;
    const int wave = threadIdx.x >> 6;
    float wcol[64];
#pragma unroll
    for (int k = 0; k < 64; ++k) wcol[k] = W[k * 64 + lane];
    int base = blockIdx.x * 64;
    for (int r = wave; r < 64; r += 4) {
        int row = base + r;
        if (row >= n) break;
        float a = A[(size_t)row * 64 + lane];
        float acc = 0.0f;
#pragma unroll
        for (int k = 0; k < 64; ++k) {
            float ak = __uint_as_float(__builtin_amdgcn_readlane(__float_as_uint(a), k));
            acc = fmaf(ak, wcol[k], acc);
        }
        out[(size_t)row * 64 + lane] = acc * dinv[row];
    }
}

// ---- Aggregate: one wave per node, register accumulator, no atomics ----
// out[i][f] = relu(dinv[i]*(g[i][f] + sum_nb g[s][f]) + b[f]); LAST fuses head.
template <bool LAST>
__global__ __launch_bounds__(256) void k_aggregate(const float* __restrict__ g,
                                                   const int2* __restrict__ rowinfo,
                                                   const int* __restrict__ csr,
                                                   const float* __restrict__ dinv,
                                                   const float* __restrict__ bias,
                                                   const float* __restrict__ Wo,
                                                   const float* __restrict__ bo,
                                                   float* __restrict__ out, int n) {
    int t = blockIdx.x * blockDim.x + threadIdx.x;
    int node = t >> 6;
    int lane = t & 63;
    if (node >= n) return;
    int2 ri = rowinfo[node];
    int e = ri.x;
    int e1 = ri.x + ri.y;
    float acc = g[(size_t)node * 64 + lane];  // self-loop term
    for (; e + 4 <= e1; e += 4) {
        int i0 = csr[e], i1 = csr[e + 1], i2 = csr[e + 2], i3 = csr[e + 3];
        float a0 = g[(size_t)i0 * 64 + lane];
        float a1 = g[(size_t)i1 * 64 + lane];
        float a2 = g[(size_t)i2 * 64 + lane];
        float a3 = g[(size_t)i3 * 64 + lane];
        acc += (a0 + a1) + (a2 + a3);
    }
    for (; e < e1; ++e) acc += g[(size_t)csr[e] * 64 + lane];
    float vv = fmaxf(fmaf(dinv[node], acc, bias[lane]), 0.0f);
    if constexpr (LAST) {
        float p = vv * Wo[lane];
#pragma unroll
        for (int s = 32; s > 0; s >>= 1) p += __shfl_xor(p, s, 64);
        if (lane == 0) out[node] = p + bo[0];
    } else {
        out[(size_t)node * 64 + lane] = vv;
    }
}

extern "C" void kernel_launch(void* const* d_in, const int* in_sizes, int n_in,
                              void* d_out, int out_size, void* d_ws, size_t ws_size,
                              hipStream_t stream) {
    const float* x  = (const float*)d_in[0];
    const int*   ei = (const int*)d_in[1];
    const float* W1 = (const float*)d_in[2];
    const float* b1 = (const float*)d_in[3];
    const float* W2 = (const float*)d_in[4];
    const float* b2 = (const float*)d_in[5];
    const float* Wo = (const float*)d_in[6];
    const float* bo = (const float*)d_in[7];
    float* out = (float*)d_out;

    const int n = in_sizes[0] / 64;
    const int E = in_sizes[1] / 2;
    const int* src = ei;
    const int* dst = ei + E;

    const int nbuck = (n + BUCK_NODES - 1) >> NB_SHIFT;      // 391
    const int nchunks = (E + CHUNK - 1) / CHUNK;             // 306

    char* ws = (char*)d_ws;
    size_t off = 0;
    auto alloc = [&](size_t bytes) -> void* {
        void* p = ws + off;
        off += (bytes + 255) & ~(size_t)255;
        return p;
    };
    const size_t featBytes = (size_t)n * 64 * 4;             // 25.6 MB
    const size_t slabBytes = (size_t)nbuck * CAP * 4;        // 6.4 MB
    float* dinv    = (float*)alloc((size_t)n * 4);
    int*   gcur    = (int*)alloc((size_t)nbuck * 4);
    int2*  rowinfo = (int2*)alloc((size_t)n * 8);
    int*   csr     = (int*)alloc(slabBytes);
    char*  regionA = (char*)alloc(featBytes);                // packed, then bufG
    float* bufH    = (float*)alloc(featBytes);
    unsigned* packed = (unsigned*)regionA;   // dead after k_csr
    float*    bufG   = (float*)regionA;      // written from gemm1 onward

    // ---- slab counting sort -> dst-sorted csr slabs + rowinfo + dinv ----
    k_binit<<<(nbuck + 255) / 256, 256, 0, stream>>>(gcur, nbuck);
    k_bsort<<<nchunks, STPB, 0, stream>>>(src, dst, E, nbuck, gcur, packed);
    k_csr<<<nbuck, 512, 0, stream>>>(packed, gcur, n, csr, rowinfo, dinv);

    const int gemmGrid = (n + 63) / 64;
    const int nodeGrid = (n * 64 + 255) / 256;

    // ---- layer 1 ----
    k_gemm64<<<gemmGrid, 256, 0, stream>>>(x, W1, dinv, bufG, n);
    k_aggregate<false><<<nodeGrid, 256, 0, stream>>>(bufG, rowinfo, csr, dinv, b1,
                                                     nullptr, nullptr, bufH, n);
    // ---- layer 2 (head fused into epilogue) ----
    k_gemm64<<<gemmGrid, 256, 0, stream>>>(bufH, W2, dinv, bufG, n);
    k_aggregate<true><<<nodeGrid, 256, 0, stream>>>(bufG, rowinfo, csr, dinv, b2,
                                                    Wo, bo, out, n);
}

// Round 8
// 209.097 us; speedup vs baseline: 1.7813x; 1.0729x over previous
//
#include <hip/hip_runtime.h>

// GCN 2-layer + linear head on MI355X.
// R7 post-mortem: aggregate (2x63us) is latency/MLP-bound, NOT BW-bound
// (FETCH 151MB@6.3TB/s=24us floor, L2 350MB@34.5TB/s=10us; observed 63us,
// VALU 32%). Each wave had only 4 dword-gathers in flight.
// R8: float4 gathers -- 16 lanes/row, one dwordx4 instr fetches 4 edges'
// rows; edge lists padded to x4 with a dummy zero row (index n) so the
// inner loop is guard-free; cross-group reduce = 2 shfl_xor.

constexpr int NB_SHIFT = 8;                 // 256 nodes per bucket
constexpr int BUCK_NODES = 1 << NB_SHIFT;
constexpr int CAP = 4096;                   // slab capacity (mean 3197+pad~3600, >8 sigma)
constexpr int CHUNK = 4096;                 // edges per sort block
constexpr int STPB = 512;
// assumes nbuck <= 512, src < 2^17, padded bucket size <= CAP

__device__ __forceinline__ float4 f4add(float4 a, float4 b) {
    return make_float4(a.x + b.x, a.y + b.y, a.z + b.z, a.w + b.w);
}
__device__ __forceinline__ float4 f4shfl_xor(float4 a, int m) {
    return make_float4(__shfl_xor(a.x, m, 64), __shfl_xor(a.y, m, 64),
                       __shfl_xor(a.z, m, 64), __shfl_xor(a.w, m, 64));
}

// ---- fused: chunk histogram -> slab reserve -> LDS sort -> dense flush -
__global__ __launch_bounds__(STPB) void k_bsort(const int* __restrict__ src,
                                                const int* __restrict__ dst, int E, int nbuck,
                                                int* __restrict__ gcur,
                                                unsigned* __restrict__ packed) {
    __shared__ int shStart[512];
    __shared__ int shCur[512];
    __shared__ int shOff[512];
    __shared__ unsigned stage[CHUNK];
    __shared__ unsigned short sbkt[CHUNK];
    const int tid = threadIdx.x;
    const int base = blockIdx.x * CHUNK;
    const int end = min(base + CHUNK, E);
    // pass A: count buckets in this chunk (LDS atomics)
    shCur[tid] = 0;
    __syncthreads();
    for (int e = base + tid; e < end; e += STPB)
        atomicAdd(&shCur[dst[e] >> NB_SHIFT], 1);
    __syncthreads();
    int v = shCur[tid];
    shStart[tid] = v;
    __syncthreads();
    for (int s = 1; s < 512; s <<= 1) {      // inclusive Hillis-Steele
        int a = (tid >= s) ? shStart[tid - s] : 0;
        __syncthreads();
        shStart[tid] += a;
        __syncthreads();
    }
    int exc = shStart[tid] - v;
    shStart[tid] = exc;
    shCur[tid] = exc;
    // reserve this chunk's span in bucket slabs (one global atomic each)
    if (tid < nbuck) shOff[tid] = (size_t)tid * CAP + ((v > 0) ? atomicAdd(&gcur[tid], v) : 0);
    __syncthreads();
    // pass B: permute chunk into LDS, bucket-major
    for (int e = base + tid; e < end; e += STPB) {
        int s = src[e];
        int d = dst[e];
        int b = d >> NB_SHIFT;
        int slot = atomicAdd(&shCur[b], 1);
        stage[slot] = ((unsigned)(d & (BUCK_NODES - 1)) << 17) | (unsigned)s;
        sbkt[slot] = (unsigned short)b;
    }
    __syncthreads();
    // pass C: linear flush, same-bucket runs land contiguously
    int cnt = end - base;
    for (int i = tid; i < cnt; i += STPB) {
        int b = sbkt[i];
        packed[shOff[b] + (i - shStart[b])] = stage[i];
    }
}

// ---- per-bucket counting sort by dstLocal -> csr slab (x4-padded rows),
//      rowinfo=(start, paddedCount), dinv ------------------------------
__global__ __launch_bounds__(512) void k_csr(const unsigned* __restrict__ packed,
                                             const int* __restrict__ gcur, int n,
                                             int* __restrict__ csr, int2* __restrict__ rowinfo,
                                             float* __restrict__ dinv) {
    __shared__ int cnt[BUCK_NODES];
    __shared__ int scn[BUCK_NODES];
    __shared__ int cur[BUCK_NODES];
    const int tid = threadIdx.x;
    const int e0 = blockIdx.x * CAP;
    const int e1 = e0 + gcur[blockIdx.x];     // slab base + size
    if (tid < BUCK_NODES) cnt[tid] = 0;
    __syncthreads();
    for (int e = e0 + tid; e < e1; e += 512)
        atomicAdd(&cnt[packed[e] >> 17], 1);
    __syncthreads();
    int v = (tid < BUCK_NODES) ? cnt[tid] : 0;
    int pad = (v + 3) & ~3;                   // pad each node's list to x4
    if (tid < BUCK_NODES) scn[tid] = pad;
    __syncthreads();
    for (int s = 1; s < BUCK_NODES; s <<= 1) {   // inclusive Hillis-Steele
        int add = (tid >= s && tid < BUCK_NODES) ? scn[tid - s] : 0;
        __syncthreads();
        if (tid < BUCK_NODES) scn[tid] += add;
        __syncthreads();
    }
    int start = 0;
    if (tid < BUCK_NODES) {
        start = e0 + scn[tid] - pad;
        cur[tid] = start;
        int node = blockIdx.x * BUCK_NODES + tid;
        if (node < n) {
            rowinfo[node] = make_int2(start, pad);
            dinv[node] = rsqrtf(1.0f + (float)v);
        }
    }
    __syncthreads();
    for (int e = e0 + tid; e < e1; e += 512) {
        unsigned p = packed[e];
        int pos = atomicAdd(&cur[p >> 17], 1);   // LDS cursor
        csr[pos] = (int)(p & 0x1FFFFu);          // dense slab window, L2-hot
    }
    __syncthreads();
    // pad tail with dummy node index n (zero row in g)
    if (tid < BUCK_NODES) {
        for (int p = v; p < pad; ++p) csr[start + p] = n;
    }
}

// ---- GEMM: out[i][f] = (sum_k A[i][k] * W[k][f]) * dinv[i] -------------
__global__ __launch_bounds__(256) void k_gemm64(const float* __restrict__ A, const float* __restrict__ W,
                                                const float* __restrict__ dinv, float* __restrict__ out,
                                                int n) {
    const int lane = threadIdx.x & 63;
    const int wave = threadIdx.x >> 6;
    float wcol[64];
#pragma unroll
    for (int k = 0; k < 64; ++k) wcol[k] = W[k * 64 + lane];
    int base = blockIdx.x * 64;
    for (int r = wave; r < 64; r += 4) {
        int row = base + r;
        if (row >= n) break;
        float a = A[(size_t)row * 64 + lane];
        float acc = 0.0f;
#pragma unroll
        for (int k = 0; k < 64; ++k) {
            float ak = __uint_as_float(__builtin_amdgcn_readlane(__float_as_uint(a), k));
            acc = fmaf(ak, wcol[k], acc);
        }
        out[(size_t)row * 64 + lane] = acc * dinv[row];
    }
}

// ---- Aggregate: one wave per node; float4 gathers (4 edges / instr) ----
// lane = 16*grp + q; grp handles edge e+4r+grp, q indexes the row quad.
// out[i][:] = relu(dinv[i]*(g[i][:] + sum_nb g[s][:]) + b); LAST fuses head.
template <bool LAST>
__global__ __launch_bounds__(256) void k_aggregate(const float4* __restrict__ g4,
                                                   const int2* __restrict__ rowinfo,
                                                   const int* __restrict__ csr,
                                                   const float* __restrict__ dinv,
                                                   const float4* __restrict__ bias4,
                                                   const float4* __restrict__ Wo4,
                                                   const float* __restrict__ bo,
                                                   float4* __restrict__ out4,
                                                   float* __restrict__ outHead, int n) {
    int t = blockIdx.x * blockDim.x + threadIdx.x;
    int node = t >> 6;
    int lane = t & 63;
    if (node >= n) return;
    const int grp = lane >> 4;
    const int q = lane & 15;
    int2 ri = rowinfo[node];
    const int e = ri.x;
    const int rounds = ri.y >> 2;
    float4 acc = make_float4(0.f, 0.f, 0.f, 0.f);
    int r = 0;
    for (; r + 2 <= rounds; r += 2) {         // 8 edges in flight / wave
        int i0 = csr[e + r * 4 + grp];
        int i1 = csr[e + r * 4 + 4 + grp];
        float4 a0 = g4[(size_t)i0 * 16 + q];
        float4 a1 = g4[(size_t)i1 * 16 + q];
        acc = f4add(acc, f4add(a0, a1));
    }
    if (r < rounds) {
        int i0 = csr[e + r * 4 + grp];
        acc = f4add(acc, g4[(size_t)i0 * 16 + q]);
    }
    // reduce the 4 lane groups (features q*4.. are shared across groups)
    acc = f4add(acc, f4shfl_xor(acc, 16));
    acc = f4add(acc, f4shfl_xor(acc, 32));
    acc = f4add(acc, g4[(size_t)node * 16 + q]);   // self-loop term
    float dv = dinv[node];
    float4 b = bias4[q];
    float4 vv = make_float4(fmaxf(fmaf(dv, acc.x, b.x), 0.f),
                            fmaxf(fmaf(dv, acc.y, b.y), 0.f),
                            fmaxf(fmaf(dv, acc.z, b.z), 0.f),
                            fmaxf(fmaf(dv, acc.w, b.w), 0.f));
    if constexpr (LAST) {
        float4 w = Wo4[q];
        float p = vv.x * w.x + vv.y * w.y + vv.z * w.z + vv.w * w.w;
#pragma unroll
        for (int s = 8; s > 0; s >>= 1) p += __shfl_xor(p, s, 64);
        if (lane == 0) outHead[node] = p + bo[0];
    } else {
        if (grp == 0) out4[(size_t)node * 16 + q] = vv;
    }
}

extern "C" void kernel_launch(void* const* d_in, const int* in_sizes, int n_in,
                              void* d_out, int out_size, void* d_ws, size_t ws_size,
                              hipStream_t stream) {
    const float* x  = (const float*)d_in[0];
    const int*   ei = (const int*)d_in[1];
    const float* W1 = (const float*)d_in[2];
    const float* b1 = (const float*)d_in[3];
    const float* W2 = (const float*)d_in[4];
    const float* b2 = (const float*)d_in[5];
    const float* Wo = (const float*)d_in[6];
    const float* bo = (const float*)d_in[7];
    float* out = (float*)d_out;

    const int n = in_sizes[0] / 64;
    const int E = in_sizes[1] / 2;
    const int* src = ei;
    const int* dst = ei + E;

    const int nbuck = (n + BUCK_NODES - 1) >> NB_SHIFT;      // 391
    const int nchunks = (E + CHUNK - 1) / CHUNK;             // 306

    char* ws = (char*)d_ws;
    size_t off = 0;
    auto alloc = [&](size_t bytes) -> void* {
        void* p = ws + off;
        off += (bytes + 255) & ~(size_t)255;
        return p;
    };
    const size_t featBytes = (size_t)(n + 1) * 64 * 4;       // n rows + dummy zero row
    const size_t slabBytes = (size_t)nbuck * CAP * 4;        // 6.4 MB
    float* dinv    = (float*)alloc((size_t)n * 4);
    int*   gcur    = (int*)alloc((size_t)nbuck * 4);
    int2*  rowinfo = (int2*)alloc((size_t)n * 8);
    int*   csr     = (int*)alloc(slabBytes);
    char*  regionA = (char*)alloc(featBytes > slabBytes ? featBytes : slabBytes);
    float* bufH    = (float*)alloc(featBytes);
    unsigned* packed = (unsigned*)regionA;   // dead after k_csr
    float*    bufG   = (float*)regionA;      // written from gemm1 onward

    // zero slab cursors + the dummy zero rows (row n of bufG/bufH)
    hipMemsetAsync(gcur, 0, (size_t)nbuck * 4, stream);
    hipMemsetAsync((char*)bufG + (size_t)n * 256, 0, 256, stream);
    hipMemsetAsync((char*)bufH + (size_t)n * 256, 0, 256, stream);

    // ---- slab counting sort -> dst-sorted csr slabs + rowinfo + dinv ----
    k_bsort<<<nchunks, STPB, 0, stream>>>(src, dst, E, nbuck, gcur, packed);
    k_csr<<<nbuck, 512, 0, stream>>>(packed, gcur, n, csr, rowinfo, dinv);

    const int gemmGrid = (n + 63) / 64;
    const int nodeGrid = (n + 3) / 4;        // one wave per node, 4 waves/block

    // ---- layer 1 ----
    k_gemm64<<<gemmGrid, 256, 0, stream>>>(x, W1, dinv, bufG, n);
    k_aggregate<false><<<nodeGrid, 256, 0, stream>>>((const float4*)bufG, rowinfo, csr, dinv,
                                                     (const float4*)b1, nullptr, nullptr,
                                                     (float4*)bufH, nullptr, n);
    // ---- layer 2 (head fused into epilogue) ----
    k_gemm64<<<gemmGrid, 256, 0, stream>>>(bufH, W2, dinv, bufG, n);
    k_aggregate<true><<<nodeGrid, 256, 0, stream>>>((const float4*)bufG, rowinfo, csr, dinv,
                                                    (const float4*)b2, (const float4*)Wo, bo,
                                                    nullptr, out, n);
}

// Round 9
// 181.000 us; speedup vs baseline: 2.0578x; 1.1552x over previous
//
#include <hip/hip_runtime.h>

// GCN 2-layer + linear head on MI355X.
// R8 post-mortem: aggregate hit the random-256B fabric/L3 ceiling
// (3.5 TB/s, FETCH 152MB = 3x footprint; per-XCD L2 4MB vs 25.6MB working
// set). R9: gather operand in bf16 (128B rows) -> halves bytes AND
// footprint (12.8MB -> ~31% L2 hit), 8 edges per dwordx4 instr.
// Error budget: g carries dinv (~0.27); bf16 absmax ~3e-4 << 1.5e-3.

constexpr int NB_SHIFT = 8;                 // 256 nodes per bucket
constexpr int BUCK_NODES = 1 << NB_SHIFT;
constexpr int CAP = 5120;                   // slab cap (mean padded ~4096 + 15 sigma)
constexpr int CHUNK = 4096;                 // edges per sort block
constexpr int STPB = 512;
// assumes nbuck <= 512, src < 2^17, padded bucket size <= CAP

// ---- fused: chunk histogram -> slab reserve -> LDS sort -> dense flush -
__global__ __launch_bounds__(STPB) void k_bsort(const int* __restrict__ src,
                                                const int* __restrict__ dst, int E, int nbuck,
                                                int* __restrict__ gcur,
                                                unsigned* __restrict__ packed) {
    __shared__ int shStart[512];
    __shared__ int shCur[512];
    __shared__ int shOff[512];
    __shared__ unsigned stage[CHUNK];
    __shared__ unsigned short sbkt[CHUNK];
    const int tid = threadIdx.x;
    const int base = blockIdx.x * CHUNK;
    const int end = min(base + CHUNK, E);
    // pass A: count buckets in this chunk (LDS atomics)
    shCur[tid] = 0;
    __syncthreads();
    for (int e = base + tid; e < end; e += STPB)
        atomicAdd(&shCur[dst[e] >> NB_SHIFT], 1);
    __syncthreads();
    int v = shCur[tid];
    shStart[tid] = v;
    __syncthreads();
    for (int s = 1; s < 512; s <<= 1) {      // inclusive Hillis-Steele
        int a = (tid >= s) ? shStart[tid - s] : 0;
        __syncthreads();
        shStart[tid] += a;
        __syncthreads();
    }
    int exc = shStart[tid] - v;
    shStart[tid] = exc;
    shCur[tid] = exc;
    // reserve this chunk's span in bucket slabs (one global atomic each)
    if (tid < nbuck) shOff[tid] = tid * CAP + ((v > 0) ? atomicAdd(&gcur[tid], v) : 0);
    __syncthreads();
    // pass B: permute chunk into LDS, bucket-major
    for (int e = base + tid; e < end; e += STPB) {
        int s = src[e];
        int d = dst[e];
        int b = d >> NB_SHIFT;
        int slot = atomicAdd(&shCur[b], 1);
        stage[slot] = ((unsigned)(d & (BUCK_NODES - 1)) << 17) | (unsigned)s;
        sbkt[slot] = (unsigned short)b;
    }
    __syncthreads();
    // pass C: linear flush, same-bucket runs land contiguously
    int cnt = end - base;
    for (int i = tid; i < cnt; i += STPB) {
        int b = sbkt[i];
        packed[shOff[b] + (i - shStart[b])] = stage[i];
    }
}

// ---- per-bucket counting sort by dstLocal -> csr slab (x8-padded rows),
//      rowinfo=(start, paddedCount), dinv ------------------------------
__global__ __launch_bounds__(512) void k_csr(const unsigned* __restrict__ packed,
                                             const int* __restrict__ gcur, int n,
                                             int* __restrict__ csr, int2* __restrict__ rowinfo,
                                             float* __restrict__ dinv) {
    __shared__ int cnt[BUCK_NODES];
    __shared__ int scn[BUCK_NODES];
    __shared__ int cur[BUCK_NODES];
    const int tid = threadIdx.x;
    const int e0 = blockIdx.x * CAP;
    const int e1 = e0 + gcur[blockIdx.x];     // slab base + size
    if (tid < BUCK_NODES) cnt[tid] = 0;
    __syncthreads();
    for (int e = e0 + tid; e < e1; e += 512)
        atomicAdd(&cnt[packed[e] >> 17], 1);
    __syncthreads();
    int v = (tid < BUCK_NODES) ? cnt[tid] : 0;
    int pad = (v + 7) & ~7;                   // pad each node's list to x8
    if (tid < BUCK_NODES) scn[tid] = pad;
    __syncthreads();
    for (int s = 1; s < BUCK_NODES; s <<= 1) {   // inclusive Hillis-Steele
        int add = (tid >= s && tid < BUCK_NODES) ? scn[tid - s] : 0;
        __syncthreads();
        if (tid < BUCK_NODES) scn[tid] += add;
        __syncthreads();
    }
    int start = 0;
    if (tid < BUCK_NODES) {
        start = e0 + scn[tid] - pad;
        cur[tid] = start;
        int node = blockIdx.x * BUCK_NODES + tid;
        if (node < n) {
            rowinfo[node] = make_int2(start, pad);
            dinv[node] = rsqrtf(1.0f + (float)v);
        }
    }
    __syncthreads();
    for (int e = e0 + tid; e < e1; e += 512) {
        unsigned p = packed[e];
        int pos = atomicAdd(&cur[p >> 17], 1);   // LDS cursor
        csr[pos] = (int)(p & 0x1FFFFu);          // dense slab window, L2-hot
    }
    __syncthreads();
    // pad tail with dummy node index n (zero bf16 row in g)
    if (tid < BUCK_NODES) {
        for (int p = v; p < pad; ++p) csr[start + p] = n;
    }
}

// ---- GEMM: gBf[i][f] = bf16((sum_k A[i][k] * W[k][f]) * dinv[i]) -------
__global__ __launch_bounds__(256) void k_gemm64bf(const float* __restrict__ A,
                                                  const float* __restrict__ W,
                                                  const float* __restrict__ dinv,
                                                  unsigned short* __restrict__ out,
                                                  int n) {
    const int lane = threadIdx.x & 63;
    const int wave = threadIdx.x >> 6;
    float wcol[64];
#pragma unroll
    for (int k = 0; k < 64; ++k) wcol[k] = W[k * 64 + lane];
    int base = blockIdx.x * 64;
    for (int r = wave; r < 64; r += 4) {
        int row = base + r;
        if (row >= n) break;
        float a = A[(size_t)row * 64 + lane];
        float acc = 0.0f;
#pragma unroll
        for (int k = 0; k < 64; ++k) {
            float ak = __uint_as_float(__builtin_amdgcn_readlane(__float_as_uint(a), k));
            acc = fmaf(ak, wcol[k], acc);
        }
        float val = acc * dinv[row];
        unsigned u = __float_as_uint(val);
        u = (u + 0x7FFFu + ((u >> 16) & 1u)) >> 16;   // RNE to bf16
        out[(size_t)row * 64 + lane] = (unsigned short)u;
    }
}

__device__ __forceinline__ void acc8(float* acc, uint4 a) {
    acc[0] += __uint_as_float(a.x << 16);
    acc[1] += __uint_as_float(a.x & 0xFFFF0000u);
    acc[2] += __uint_as_float(a.y << 16);
    acc[3] += __uint_as_float(a.y & 0xFFFF0000u);
    acc[4] += __uint_as_float(a.z << 16);
    acc[5] += __uint_as_float(a.z & 0xFFFF0000u);
    acc[6] += __uint_as_float(a.w << 16);
    acc[7] += __uint_as_float(a.w & 0xFFFF0000u);
}

// ---- Aggregate: one wave per node; bf16 rows, 8 edges per dwordx4 ------
// lane = 8*grp + q; grp handles edge e+8r+grp, q indexes the 16B row chunk
// (features 8q..8q+7). out fp32 row (non-LAST) or fused head (LAST).
template <bool LAST>
__global__ __launch_bounds__(256) void k_aggregate(const uint4* __restrict__ g4,
                                                   const int2* __restrict__ rowinfo,
                                                   const int* __restrict__ csr,
                                                   const float* __restrict__ dinv,
                                                   const float4* __restrict__ bias4,
                                                   const float4* __restrict__ Wo4,
                                                   const float* __restrict__ bo,
                                                   float4* __restrict__ out4,
                                                   float* __restrict__ outHead, int n) {
    int t = blockIdx.x * blockDim.x + threadIdx.x;
    int node = t >> 6;
    int lane = t & 63;
    if (node >= n) return;
    const int grp = lane >> 3;                // 0..7
    const int q = lane & 7;                   // 0..7
    int2 ri = rowinfo[node];
    const int e = ri.x;
    const int rounds = ri.y >> 3;
    float acc[8] = {0.f, 0.f, 0.f, 0.f, 0.f, 0.f, 0.f, 0.f};
    int r = 0;
    for (; r + 2 <= rounds; r += 2) {         // 16 edge-rows in flight / wave
        int i0 = csr[e + r * 8 + grp];
        int i1 = csr[e + r * 8 + 8 + grp];
        uint4 a0 = g4[(size_t)i0 * 8 + q];
        uint4 a1 = g4[(size_t)i1 * 8 + q];
        acc8(acc, a0);
        acc8(acc, a1);
    }
    if (r < rounds) {
        int i0 = csr[e + r * 8 + grp];
        acc8(acc, g4[(size_t)i0 * 8 + q]);
    }
    // reduce across the 8 lane groups (feature chunks shared across grps)
#pragma unroll
    for (int m = 8; m < 64; m <<= 1) {
#pragma unroll
        for (int k = 0; k < 8; ++k) acc[k] += __shfl_xor(acc[k], m, 64);
    }
    acc8(acc, g4[(size_t)node * 8 + q]);      // self-loop term (bf16 row)
    float dv = dinv[node];
    float4 b0 = bias4[2 * q], b1 = bias4[2 * q + 1];
    float vv[8];
    vv[0] = fmaxf(fmaf(dv, acc[0], b0.x), 0.f);
    vv[1] = fmaxf(fmaf(dv, acc[1], b0.y), 0.f);
    vv[2] = fmaxf(fmaf(dv, acc[2], b0.z), 0.f);
    vv[3] = fmaxf(fmaf(dv, acc[3], b0.w), 0.f);
    vv[4] = fmaxf(fmaf(dv, acc[4], b1.x), 0.f);
    vv[5] = fmaxf(fmaf(dv, acc[5], b1.y), 0.f);
    vv[6] = fmaxf(fmaf(dv, acc[6], b1.z), 0.f);
    vv[7] = fmaxf(fmaf(dv, acc[7], b1.w), 0.f);
    if constexpr (LAST) {
        float4 w0 = Wo4[2 * q], w1 = Wo4[2 * q + 1];
        float p = vv[0] * w0.x + vv[1] * w0.y + vv[2] * w0.z + vv[3] * w0.w +
                  vv[4] * w1.x + vv[5] * w1.y + vv[6] * w1.z + vv[7] * w1.w;
#pragma unroll
        for (int m = 1; m < 8; m <<= 1) p += __shfl_xor(p, m, 64);
        if (lane == 0) outHead[node] = p + bo[0];
    } else {
        if (grp < 2) {
            float4 o = (grp == 0) ? make_float4(vv[0], vv[1], vv[2], vv[3])
                                  : make_float4(vv[4], vv[5], vv[6], vv[7]);
            out4[(size_t)node * 16 + 2 * q + grp] = o;
        }
    }
}

extern "C" void kernel_launch(void* const* d_in, const int* in_sizes, int n_in,
                              void* d_out, int out_size, void* d_ws, size_t ws_size,
                              hipStream_t stream) {
    const float* x  = (const float*)d_in[0];
    const int*   ei = (const int*)d_in[1];
    const float* W1 = (const float*)d_in[2];
    const float* b1 = (const float*)d_in[3];
    const float* W2 = (const float*)d_in[4];
    const float* b2 = (const float*)d_in[5];
    const float* Wo = (const float*)d_in[6];
    const float* bo = (const float*)d_in[7];
    float* out = (float*)d_out;

    const int n = in_sizes[0] / 64;
    const int E = in_sizes[1] / 2;
    const int* src = ei;
    const int* dst = ei + E;

    const int nbuck = (n + BUCK_NODES - 1) >> NB_SHIFT;      // 391
    const int nchunks = (E + CHUNK - 1) / CHUNK;             // 306

    char* ws = (char*)d_ws;
    size_t off = 0;
    auto alloc = [&](size_t bytes) -> void* {
        void* p = ws + off;
        off += (bytes + 255) & ~(size_t)255;
        return p;
    };
    const size_t slabBytes = (size_t)nbuck * CAP * 4;        // 8.0 MB
    const size_t hBytes    = (size_t)n * 64 * 4;             // 25.6 MB (fp32 h1)
    const size_t gBytes    = (size_t)(n + 1) * 64 * 2;       // 12.8 MB (bf16 g + dummy)
    float*          dinv    = (float*)alloc((size_t)n * 4);
    int*            gcur    = (int*)alloc((size_t)nbuck * 4);
    int2*           rowinfo = (int2*)alloc((size_t)n * 8);
    int*            csr     = (int*)alloc(slabBytes);
    char*           regionA = (char*)alloc(hBytes > slabBytes ? hBytes : slabBytes);
    unsigned short* gBf     = (unsigned short*)alloc(gBytes);
    unsigned* packed = (unsigned*)regionA;   // dead after k_csr
    float*    bufH   = (float*)regionA;      // h1 (fp32), written from agg1 on

    // zero slab cursors + the dummy bf16 row (index n)
    hipMemsetAsync(gcur, 0, (size_t)nbuck * 4, stream);
    hipMemsetAsync(gBf + (size_t)n * 64, 0, 128, stream);

    // ---- slab counting sort -> dst-sorted csr slabs + rowinfo + dinv ----
    k_bsort<<<nchunks, STPB, 0, stream>>>(src, dst, E, nbuck, gcur, packed);
    k_csr<<<nbuck, 512, 0, stream>>>(packed, gcur, n, csr, rowinfo, dinv);

    const int gemmGrid = (n + 63) / 64;
    const int nodeGrid = (n + 3) / 4;        // one wave per node, 4 waves/block

    // ---- layer 1 ----
    k_gemm64bf<<<gemmGrid, 256, 0, stream>>>(x, W1, dinv, gBf, n);
    k_aggregate<false><<<nodeGrid, 256, 0, stream>>>((const uint4*)gBf, rowinfo, csr, dinv,
                                                     (const float4*)b1, nullptr, nullptr,
                                                     (float4*)bufH, nullptr, n);
    // ---- layer 2 (head fused into epilogue) ----
    k_gemm64bf<<<gemmGrid, 256, 0, stream>>>(bufH, W2, dinv, gBf, n);
    k_aggregate<true><<<nodeGrid, 256, 0, stream>>>((const uint4*)gBf, rowinfo, csr, dinv,
                                                    (const float4*)b2, (const float4*)Wo, bo,
                                                    nullptr, out, n);
}

// Round 10
// 177.185 us; speedup vs baseline: 2.1021x; 1.0215x over previous
//
#include <hip/hip_runtime.h>

// GCN 2-layer + linear head on MI355X.
// R9 post-mortem: 181us passed (absmax 4.9e-4), but profile shows
// fillBufferAligned dispatches at ~43us with near-zero traffic -- our two
// graph-captured hipMemsetAsync calls are suspects. R10: replace them with
// one trivial k_init kernel (zero 391 slab cursors + 64-elem dummy row).
// Pipeline otherwise identical: slab counting sort -> bf16 gather aggregate.

constexpr int NB_SHIFT = 8;                 // 256 nodes per bucket
constexpr int BUCK_NODES = 1 << NB_SHIFT;
constexpr int CAP = 5120;                   // slab cap (mean padded ~4096 + 15 sigma)
constexpr int CHUNK = 4096;                 // edges per sort block
constexpr int STPB = 512;
// assumes nbuck <= 512, src < 2^17, padded bucket size <= CAP

// ---- init: slab cursors + dummy bf16 row (replaces hipMemsetAsync) -----
__global__ __launch_bounds__(512) void k_init(int* __restrict__ gcur, int nbuck,
                                              unsigned short* __restrict__ dummyRow) {
    int t = threadIdx.x;
    if (t < nbuck) gcur[t] = 0;
    if (t < 64) dummyRow[t] = 0;
}

// ---- fused: chunk histogram -> slab reserve -> LDS sort -> dense flush -
__global__ __launch_bounds__(STPB) void k_bsort(const int* __restrict__ src,
                                                const int* __restrict__ dst, int E, int nbuck,
                                                int* __restrict__ gcur,
                                                unsigned* __restrict__ packed) {
    __shared__ int shStart[512];
    __shared__ int shCur[512];
    __shared__ int shOff[512];
    __shared__ unsigned stage[CHUNK];
    __shared__ unsigned short sbkt[CHUNK];
    const int tid = threadIdx.x;
    const int base = blockIdx.x * CHUNK;
    const int end = min(base + CHUNK, E);
    // pass A: count buckets in this chunk (LDS atomics)
    shCur[tid] = 0;
    __syncthreads();
    for (int e = base + tid; e < end; e += STPB)
        atomicAdd(&shCur[dst[e] >> NB_SHIFT], 1);
    __syncthreads();
    int v = shCur[tid];
    shStart[tid] = v;
    __syncthreads();
    for (int s = 1; s < 512; s <<= 1) {      // inclusive Hillis-Steele
        int a = (tid >= s) ? shStart[tid - s] : 0;
        __syncthreads();
        shStart[tid] += a;
        __syncthreads();
    }
    int exc = shStart[tid] - v;
    shStart[tid] = exc;
    shCur[tid] = exc;
    // reserve this chunk's span in bucket slabs (one global atomic each)
    if (tid < nbuck) shOff[tid] = tid * CAP + ((v > 0) ? atomicAdd(&gcur[tid], v) : 0);
    __syncthreads();
    // pass B: permute chunk into LDS, bucket-major
    for (int e = base + tid; e < end; e += STPB) {
        int s = src[e];
        int d = dst[e];
        int b = d >> NB_SHIFT;
        int slot = atomicAdd(&shCur[b], 1);
        stage[slot] = ((unsigned)(d & (BUCK_NODES - 1)) << 17) | (unsigned)s;
        sbkt[slot] = (unsigned short)b;
    }
    __syncthreads();
    // pass C: linear flush, same-bucket runs land contiguously
    int cnt = end - base;
    for (int i = tid; i < cnt; i += STPB) {
        int b = sbkt[i];
        packed[shOff[b] + (i - shStart[b])] = stage[i];
    }
}

// ---- per-bucket counting sort by dstLocal -> csr slab (x8-padded rows),
//      rowinfo=(start, paddedCount), dinv ------------------------------
__global__ __launch_bounds__(512) void k_csr(const unsigned* __restrict__ packed,
                                             const int* __restrict__ gcur, int n,
                                             int* __restrict__ csr, int2* __restrict__ rowinfo,
                                             float* __restrict__ dinv) {
    __shared__ int cnt[BUCK_NODES];
    __shared__ int scn[BUCK_NODES];
    __shared__ int cur[BUCK_NODES];
    const int tid = threadIdx.x;
    const int e0 = blockIdx.x * CAP;
    const int e1 = e0 + gcur[blockIdx.x];     // slab base + size
    if (tid < BUCK_NODES) cnt[tid] = 0;
    __syncthreads();
    for (int e = e0 + tid; e < e1; e += 512)
        atomicAdd(&cnt[packed[e] >> 17], 1);
    __syncthreads();
    int v = (tid < BUCK_NODES) ? cnt[tid] : 0;
    int pad = (v + 7) & ~7;                   // pad each node's list to x8
    if (tid < BUCK_NODES) scn[tid] = pad;
    __syncthreads();
    for (int s = 1; s < BUCK_NODES; s <<= 1) {   // inclusive Hillis-Steele
        int add = (tid >= s && tid < BUCK_NODES) ? scn[tid - s] : 0;
        __syncthreads();
        if (tid < BUCK_NODES) scn[tid] += add;
        __syncthreads();
    }
    int start = 0;
    if (tid < BUCK_NODES) {
        start = e0 + scn[tid] - pad;
        cur[tid] = start;
        int node = blockIdx.x * BUCK_NODES + tid;
        if (node < n) {
            rowinfo[node] = make_int2(start, pad);
            dinv[node] = rsqrtf(1.0f + (float)v);
        }
    }
    __syncthreads();
    for (int e = e0 + tid; e < e1; e += 512) {
        unsigned p = packed[e];
        int pos = atomicAdd(&cur[p >> 17], 1);   // LDS cursor
        csr[pos] = (int)(p & 0x1FFFFu);          // dense slab window, L2-hot
    }
    __syncthreads();
    // pad tail with dummy node index n (zero bf16 row in g)
    if (tid < BUCK_NODES) {
        for (int p = v; p < pad; ++p) csr[start + p] = n;
    }
}

// ---- GEMM: gBf[i][f] = bf16((sum_k A[i][k] * W[k][f]) * dinv[i]) -------
__global__ __launch_bounds__(256) void k_gemm64bf(const float* __restrict__ A,
                                                  const float* __restrict__ W,
                                                  const float* __restrict__ dinv,
                                                  unsigned short* __restrict__ out,
                                                  int n) {
    const int lane = threadIdx.x & 63;
    const int wave = threadIdx.x >> 6;
    float wcol[64];
#pragma unroll
    for (int k = 0; k < 64; ++k) wcol[k] = W[k * 64 + lane];
    int base = blockIdx.x * 64;
    for (int r = wave; r < 64; r += 4) {
        int row = base + r;
        if (row >= n) break;
        float a = A[(size_t)row * 64 + lane];
        float acc = 0.0f;
#pragma unroll
        for (int k = 0; k < 64; ++k) {
            float ak = __uint_as_float(__builtin_amdgcn_readlane(__float_as_uint(a), k));
            acc = fmaf(ak, wcol[k], acc);
        }
        float val = acc * dinv[row];
        unsigned u = __float_as_uint(val);
        u = (u + 0x7FFFu + ((u >> 16) & 1u)) >> 16;   // RNE to bf16
        out[(size_t)row * 64 + lane] = (unsigned short)u;
    }
}

__device__ __forceinline__ void acc8(float* acc, uint4 a) {
    acc[0] += __uint_as_float(a.x << 16);
    acc[1] += __uint_as_float(a.x & 0xFFFF0000u);
    acc[2] += __uint_as_float(a.y << 16);
    acc[3] += __uint_as_float(a.y & 0xFFFF0000u);
    acc[4] += __uint_as_float(a.z << 16);
    acc[5] += __uint_as_float(a.z & 0xFFFF0000u);
    acc[6] += __uint_as_float(a.w << 16);
    acc[7] += __uint_as_float(a.w & 0xFFFF0000u);
}

// ---- Aggregate: one wave per node; bf16 rows, 8 edges per dwordx4 ------
// lane = 8*grp + q; grp handles edge e+8r+grp, q indexes the 16B row chunk
// (features 8q..8q+7). out fp32 row (non-LAST) or fused head (LAST).
template <bool LAST>
__global__ __launch_bounds__(256) void k_aggregate(const uint4* __restrict__ g4,
                                                   const int2* __restrict__ rowinfo,
                                                   const int* __restrict__ csr,
                                                   const float* __restrict__ dinv,
                                                   const float4* __restrict__ bias4,
                                                   const float4* __restrict__ Wo4,
                                                   const float* __restrict__ bo,
                                                   float4* __restrict__ out4,
                                                   float* __restrict__ outHead, int n) {
    int t = blockIdx.x * blockDim.x + threadIdx.x;
    int node = t >> 6;
    int lane = t & 63;
    if (node >= n) return;
    const int grp = lane >> 3;                // 0..7
    const int q = lane & 7;                   // 0..7
    int2 ri = rowinfo[node];
    const int e = ri.x;
    const int rounds = ri.y >> 3;
    float acc[8] = {0.f, 0.f, 0.f, 0.f, 0.f, 0.f, 0.f, 0.f};
    int r = 0;
    for (; r + 2 <= rounds; r += 2) {         // 16 edge-rows in flight / wave
        int i0 = csr[e + r * 8 + grp];
        int i1 = csr[e + r * 8 + 8 + grp];
        uint4 a0 = g4[(size_t)i0 * 8 + q];
        uint4 a1 = g4[(size_t)i1 * 8 + q];
        acc8(acc, a0);
        acc8(acc, a1);
    }
    if (r < rounds) {
        int i0 = csr[e + r * 8 + grp];
        acc8(acc, g4[(size_t)i0 * 8 + q]);
    }
    // reduce across the 8 lane groups (feature chunks shared across grps)
#pragma unroll
    for (int m = 8; m < 64; m <<= 1) {
#pragma unroll
        for (int k = 0; k < 8; ++k) acc[k] += __shfl_xor(acc[k], m, 64);
    }
    acc8(acc, g4[(size_t)node * 8 + q]);      // self-loop term (bf16 row)
    float dv = dinv[node];
    float4 b0 = bias4[2 * q], b1 = bias4[2 * q + 1];
    float vv[8];
    vv[0] = fmaxf(fmaf(dv, acc[0], b0.x), 0.f);
    vv[1] = fmaxf(fmaf(dv, acc[1], b0.y), 0.f);
    vv[2] = fmaxf(fmaf(dv, acc[2], b0.z), 0.f);
    vv[3] = fmaxf(fmaf(dv, acc[3], b0.w), 0.f);
    vv[4] = fmaxf(fmaf(dv, acc[4], b1.x), 0.f);
    vv[5] = fmaxf(fmaf(dv, acc[5], b1.y), 0.f);
    vv[6] = fmaxf(fmaf(dv, acc[6], b1.z), 0.f);
    vv[7] = fmaxf(fmaf(dv, acc[7], b1.w), 0.f);
    if constexpr (LAST) {
        float4 w0 = Wo4[2 * q], w1 = Wo4[2 * q + 1];
        float p = vv[0] * w0.x + vv[1] * w0.y + vv[2] * w0.z + vv[3] * w0.w +
                  vv[4] * w1.x + vv[5] * w1.y + vv[6] * w1.z + vv[7] * w1.w;
#pragma unroll
        for (int m = 1; m < 8; m <<= 1) p += __shfl_xor(p, m, 64);
        if (lane == 0) outHead[node] = p + bo[0];
    } else {
        if (grp < 2) {
            float4 o = (grp == 0) ? make_float4(vv[0], vv[1], vv[2], vv[3])
                                  : make_float4(vv[4], vv[5], vv[6], vv[7]);
            out4[(size_t)node * 16 + 2 * q + grp] = o;
        }
    }
}

extern "C" void kernel_launch(void* const* d_in, const int* in_sizes, int n_in,
                              void* d_out, int out_size, void* d_ws, size_t ws_size,
                              hipStream_t stream) {
    const float* x  = (const float*)d_in[0];
    const int*   ei = (const int*)d_in[1];
    const float* W1 = (const float*)d_in[2];
    const float* b1 = (const float*)d_in[3];
    const float* W2 = (const float*)d_in[4];
    const float* b2 = (const float*)d_in[5];
    const float* Wo = (const float*)d_in[6];
    const float* bo = (const float*)d_in[7];
    float* out = (float*)d_out;

    const int n = in_sizes[0] / 64;
    const int E = in_sizes[1] / 2;
    const int* src = ei;
    const int* dst = ei + E;

    const int nbuck = (n + BUCK_NODES - 1) >> NB_SHIFT;      // 391
    const int nchunks = (E + CHUNK - 1) / CHUNK;             // 306

    char* ws = (char*)d_ws;
    size_t off = 0;
    auto alloc = [&](size_t bytes) -> void* {
        void* p = ws + off;
        off += (bytes + 255) & ~(size_t)255;
        return p;
    };
    const size_t slabBytes = (size_t)nbuck * CAP * 4;        // 8.0 MB
    const size_t hBytes    = (size_t)n * 64 * 4;             // 25.6 MB (fp32 h1)
    const size_t gBytes    = (size_t)(n + 1) * 64 * 2;       // 12.8 MB (bf16 g + dummy)
    float*          dinv    = (float*)alloc((size_t)n * 4);
    int*            gcur    = (int*)alloc((size_t)nbuck * 4);
    int2*           rowinfo = (int2*)alloc((size_t)n * 8);
    int*            csr     = (int*)alloc(slabBytes);
    char*           regionA = (char*)alloc(hBytes > slabBytes ? hBytes : slabBytes);
    unsigned short* gBf     = (unsigned short*)alloc(gBytes);
    unsigned* packed = (unsigned*)regionA;   // dead after k_csr
    float*    bufH   = (float*)regionA;      // h1 (fp32), written from agg1 on

    // ---- init (slab cursors + dummy bf16 row) -- no hipMemsetAsync ----
    k_init<<<1, 512, 0, stream>>>(gcur, nbuck, gBf + (size_t)n * 64);

    // ---- slab counting sort -> dst-sorted csr slabs + rowinfo + dinv ----
    k_bsort<<<nchunks, STPB, 0, stream>>>(src, dst, E, nbuck, gcur, packed);
    k_csr<<<nbuck, 512, 0, stream>>>(packed, gcur, n, csr, rowinfo, dinv);

    const int gemmGrid = (n + 63) / 64;
    const int nodeGrid = (n + 3) / 4;        // one wave per node, 4 waves/block

    // ---- layer 1 ----
    k_gemm64bf<<<gemmGrid, 256, 0, stream>>>(x, W1, dinv, gBf, n);
    k_aggregate<false><<<nodeGrid, 256, 0, stream>>>((const uint4*)gBf, rowinfo, csr, dinv,
                                                     (const float4*)b1, nullptr, nullptr,
                                                     (float4*)bufH, nullptr, n);
    // ---- layer 2 (head fused into epilogue) ----
    k_gemm64bf<<<gemmGrid, 256, 0, stream>>>(bufH, W2, dinv, gBf, n);
    k_aggregate<true><<<nodeGrid, 256, 0, stream>>>((const uint4*)gBf, rowinfo, csr, dinv,
                                                    (const float4*)b2, (const float4*)Wo, bo,
                                                    nullptr, out, n);
}